// Round 4
// baseline (412.230 us; speedup 1.0000x reference)
//
#include <hip/hip_runtime.h>
#include <hip/hip_bf16.h>
#include <cmath>

// out[b,o] = max(softplus(log_scale[o]),1e-4) * sum_k x[b,k]*W[o,k] + bias[o]
// B=32, K=N=8192, W ternary int32 [N,K] row-major -> memory-bound on W (256 MB/launch).
// Round 4: global_load_lds DMA staging (W never in VGPRs -> no spill), barrier-free
// per-wave double-buffered LDS, XOR-swizzled global addresses for bank-balanced
// ds_read_b128, distance-1 A-frag register prefetch, partials + reduce (no atomics).

#define K_SZ   8192
#define N_SZ   8192
#define B_SZ   32
#define KSPLIT 8
#define KSPAN  (K_SZ / KSPLIT)   // 1024 k per block
#define NHALF  16                // 64-k halves per block
#define BN     64                // output rows per block (16 per wave)

typedef __attribute__((ext_vector_type(8))) short bf16x8;   // MFMA A/B frag
typedef __attribute__((ext_vector_type(4))) float f32x4;    // MFMA C/D frag

// fp32 pair -> packed bf16 (round-half-up), lo in low 16
__device__ __forceinline__ unsigned pack_rn(float lo, float hi) {
  unsigned ul = __builtin_bit_cast(unsigned, lo) + 0x8000u;
  unsigned uh = __builtin_bit_cast(unsigned, hi) + 0x8000u;
  return (ul >> 16) | (uh & 0xFFFF0000u);
}
// ternary int pair -> packed bf16 (exact for -1/0/1)
__device__ __forceinline__ unsigned pack_w(int w0, int w1) {
  unsigned u0 = __builtin_bit_cast(unsigned, (float)w0);
  unsigned u1 = __builtin_bit_cast(unsigned, (float)w1);
  return (u0 >> 16) | (u1 & 0xFFFF0000u);
}

// async global->LDS, 16 B/lane; LDS dest = uniform base + lane*16
__device__ __forceinline__ void dma16(const int* g, int* l) {
  __builtin_amdgcn_global_load_lds(
      (const __attribute__((address_space(1))) unsigned*)g,
      (__attribute__((address_space(3))) unsigned*)l, 16, 0, 0);
}

// Rearrange X fp32[32,8192] -> Xr bf16 chunks in MFMA A-frag order.
// Chunk c = kb*2 + mt (kb = 32-k block, mt = m-tile): 1 KB where lane l holds
// X[mt*16 + (l&15)][kb*32 + (l>>4)*8 .. +8] as bf16x8.
__global__ void xprep(const float* __restrict__ X, uint4* __restrict__ Xr) {
  int t = blockIdx.x * blockDim.x + threadIdx.x;   // 0..32767
  int lane = t & 63;
  int chunk = t >> 6;
  int kb = chunk >> 1;
  int mt = chunk & 1;
  int row = mt * 16 + (lane & 15);
  int k0 = kb * 32 + (lane >> 4) * 8;
  const float* p = X + (size_t)row * K_SZ + k0;
  float4 a = *(const float4*)p;
  float4 b = *(const float4*)(p + 4);
  uint4 o;
  o.x = pack_rn(a.x, a.y); o.y = pack_rn(a.z, a.w);
  o.z = pack_rn(b.x, b.y); o.w = pack_rn(b.z, b.w);
  Xr[t] = o;
}

__global__ __launch_bounds__(256, 3) void tmm(
    const int*   __restrict__ W,
    const uint4* __restrict__ Xr,
    float*       __restrict__ part) {   // [KSPLIT][32][8192] fp32 partials
  // per-wave double buffer: 2 x 4 KB (16 rows x 16 slots x 16 B, no padding --
  // DMA constraint). Swizzle: slot for (row rp, k-chunk c) is c ^ rp.
  __shared__ int lds[4][2][1024];

  const int tid  = threadIdx.x;
  const int w    = tid >> 6;
  const int lane = tid & 63;
  const int q    = lane >> 4;
  const int r    = lane & 15;
  const int nb   = blockIdx.x * BN;
  const int kh   = blockIdx.y;
  const int lh   = lane >> 4, l15 = lane & 15;

  // DMA source: instr j covers rows j*4..j*4+3; lane l fetches row j*4+(l>>4),
  // k-chunk (l&15) ^ row  (16 B chunks; permutation within the row's 256 B span
  // -> same cache lines, coalescing preserved; gives bank-balanced reads).
  const int* gp[4];
  #pragma unroll
  for (int j = 0; j < 4; ++j) {
    int rp = j * 4 + lh;              // 0..15
    int c  = l15 ^ rp;
    gp[j] = W + (size_t)(nb + w * 16 + rp) * K_SZ + (size_t)kh * KSPAN + c * 4;
  }
  // prologue: DMA half 0 -> buf 0
  #pragma unroll
  for (int j = 0; j < 4; ++j) dma16(gp[j], &lds[w][0][j * 256]);

  // prologue: A-frags for half 0
  const int kbb = kh * (KSPAN / 32);
  uint4 am[2][4];
  #pragma unroll
  for (int s = 0; s < 2; ++s) {
    am[0][s * 2 + 0] = Xr[(size_t)((kbb + s) * 2 + 0) * 64 + lane];
    am[0][s * 2 + 1] = Xr[(size_t)((kbb + s) * 2 + 1) * 64 + lane];
  }

  f32x4 acc0 = {0.f, 0.f, 0.f, 0.f};   // batches 0..15
  f32x4 acc1 = {0.f, 0.f, 0.f, 0.f};   // batches 16..31

  #pragma unroll 2
  for (int h = 0; h < NHALF; ++h) {
    const int cb = h & 1, nbuf = cb ^ 1;
    if (h + 1 < NHALF) {
      // issue next-half DMA first: stays in flight across this half's compute.
      // WAR-safe: buf[nbuf]'s previous ds_reads retired via the MFMAs that
      // consumed them (program order + lgkmcnt) before these writes can land.
      #pragma unroll
      for (int j = 0; j < 4; ++j) dma16(gp[j] + (h + 1) * 64, &lds[w][nbuf][j * 256]);
      const int kb2 = kbb + (h + 1) * 2;
      #pragma unroll
      for (int s = 0; s < 2; ++s) {
        am[nbuf][s * 2 + 0] = Xr[(size_t)((kb2 + s) * 2 + 0) * 64 + lane];
        am[nbuf][s * 2 + 1] = Xr[(size_t)((kb2 + s) * 2 + 1) * 64 + lane];
      }
    }
    const int* buf = &lds[w][cb][0];
    #pragma unroll
    for (int s = 0; s < 2; ++s) {
      const int c0 = s * 8 + q * 2;                      // k-chunk pair for this frag
      int4 lo = *(const int4*)&buf[(r * 16 + ((c0)     ^ r)) * 4];
      int4 hi = *(const int4*)&buf[(r * 16 + ((c0 + 1) ^ r)) * 4];
      union { unsigned u[4]; bf16x8 v; } Bf;
      Bf.u[0] = pack_w(lo.x, lo.y); Bf.u[1] = pack_w(lo.z, lo.w);
      Bf.u[2] = pack_w(hi.x, hi.y); Bf.u[3] = pack_w(hi.z, hi.w);
      acc0 = __builtin_amdgcn_mfma_f32_16x16x32_bf16(
                 __builtin_bit_cast(bf16x8, am[cb][s * 2 + 0]), Bf.v, acc0, 0, 0, 0);
      acc1 = __builtin_amdgcn_mfma_f32_16x16x32_bf16(
                 __builtin_bit_cast(bf16x8, am[cb][s * 2 + 1]), Bf.v, acc1, 0, 0, 0);
    }
  }

  // store per-kh partials (plain coalesced-by-16 stores, no atomics)
  const int o = nb + w * 16 + r;        // C/D: col = lane&15
  float* pb = part + (size_t)kh * B_SZ * N_SZ + o;
  #pragma unroll
  for (int rg = 0; rg < 4; ++rg) {      // C/D: row = (lane>>4)*4 + reg
    pb[(size_t)(q * 4 + rg) * N_SZ]        = acc0[rg];
    pb[(size_t)(16 + q * 4 + rg) * N_SZ]   = acc1[rg];
  }
}

__global__ void reduce_k(const float* __restrict__ part,
                         const float* __restrict__ ls,
                         const float* __restrict__ bias,
                         float* __restrict__ out) {
  int idx = blockIdx.x * 256 + threadIdx.x;   // 0..262143 ; idx = b*8192 + o
  int o = idx & (N_SZ - 1);
  float s = 0.f;
  #pragma unroll
  for (int kh = 0; kh < KSPLIT; ++kh)
    s += part[(size_t)kh * B_SZ * N_SZ + idx];
  float sp = log1pf(expf(ls[o]));
  out[idx] = s * fmaxf(sp, 1e-4f) + bias[o];
}

extern "C" void kernel_launch(void* const* d_in, const int* in_sizes, int n_in,
                              void* d_out, int out_size, void* d_ws, size_t ws_size,
                              hipStream_t stream) {
  const float* X  = (const float*)d_in[0];
  const float* ls = (const float*)d_in[1];
  const float* bs = (const float*)d_in[2];
  const int*   W  = (const int*)d_in[3];
  float* out  = (float*)d_out;
  uint4* Xr   = (uint4*)d_ws;                         // 512 KB
  float* part = (float*)((char*)d_ws + (512 << 10));  // 8 MB

  xprep<<<128, 256, 0, stream>>>(X, Xr);
  dim3 grid(N_SZ / BN, KSPLIT);
  tmm<<<grid, 256, 0, stream>>>(W, Xr, part);
  reduce_k<<<(B_SZ * N_SZ) / 256, 256, 0, stream>>>(part, ls, bs, out);
}

// Round 5
// 375.550 us; speedup vs baseline: 1.0977x; 1.0977x over previous
//
#include <hip/hip_runtime.h>
#include <hip/hip_bf16.h>
#include <cmath>

// out[b,o] = max(softplus(log_scale[o]),1e-4) * sum_k x[b,k]*W[o,k] + bias[o]
// B=32, K=N=8192, W ternary int32 [N,K] row-major -> memory-bound on W (256 MB/launch).
// Round 5: barrier-free per-wave K-loop with FIFO-ordered load consumption.
//   vmcnt is FIFO: every wait must leave the newer prefetches outstanding, so
//   issue order == consumption order: [W_h, Xr_h, W_{h+1}, Xr_{h+1}, ...].
//   No __syncthreads anywhere (it compiles to s_waitcnt vmcnt(0) -> kills MLP).
//   launch_bounds(256,2): 256-VGPR cap, ~125 used -> no spill (R3's suspect).

#define K_SZ   8192
#define N_SZ   8192
#define B_SZ   32
#define KSPLIT 4
#define KSPAN  (K_SZ / KSPLIT)   // 2048 k per block
#define BK     128               // k-ints staged per wave-step
#define STEPS  (KSPAN / BK)      // 16
#define BN     64                // n-rows per block (16 per wave)
#define LDB    136               // LDS row stride in bf16; 272 B rows -> b128 reads
                                 // hit exactly 8 dwords/bank (conflict-free)

typedef __attribute__((ext_vector_type(8))) short bf16x8;   // MFMA A/B frag
typedef __attribute__((ext_vector_type(4))) float f32x4;    // MFMA C/D frag

// fp32 pair -> packed bf16 (round-half-up), lo in low 16
__device__ __forceinline__ unsigned pack_rn(float lo, float hi) {
  unsigned ul = __builtin_bit_cast(unsigned, lo) + 0x8000u;
  unsigned uh = __builtin_bit_cast(unsigned, hi) + 0x8000u;
  return (ul >> 16) | (uh & 0xFFFF0000u);
}
// ternary int pair -> packed bf16 (exact for -1/0/1)
__device__ __forceinline__ unsigned pack_w(int w0, int w1) {
  unsigned u0 = __builtin_bit_cast(unsigned, (float)w0);
  unsigned u1 = __builtin_bit_cast(unsigned, (float)w1);
  return (u0 >> 16) | (u1 & 0xFFFF0000u);
}

// Rearrange X fp32[32,8192] -> Xr bf16 chunks in MFMA A-frag order.
// Chunk c = kb*2 + mt (kb = 32-k block, mt = m-tile): 1 KB where lane l holds
// X[mt*16 + (l&15)][kb*32 + (l>>4)*8 .. +8] as bf16x8.
__global__ void xprep(const float* __restrict__ X, uint4* __restrict__ Xr) {
  int t = blockIdx.x * blockDim.x + threadIdx.x;   // 0..32767
  int lane = t & 63;
  int chunk = t >> 6;
  int kb = chunk >> 1;
  int mt = chunk & 1;
  int row = mt * 16 + (lane & 15);
  int k0 = kb * 32 + (lane >> 4) * 8;
  const float* p = X + (size_t)row * K_SZ + k0;
  float4 a = *(const float4*)p;
  float4 b = *(const float4*)(p + 4);
  uint4 o;
  o.x = pack_rn(a.x, a.y); o.y = pack_rn(a.z, a.w);
  o.z = pack_rn(b.x, b.y); o.w = pack_rn(b.z, b.w);
  Xr[t] = o;
}

__global__ __launch_bounds__(256, 2) void tmm(
    const int*   __restrict__ W,
    const uint4* __restrict__ Xr,
    float*       __restrict__ part) {   // [KSPLIT][32][8192] fp32 partials
  // per-wave private region: 16 rows x LDB bf16 = 4352 B; x4 waves = 17408 B
  __shared__ unsigned short lds[4][16 * LDB];

  const int tid  = threadIdx.x;
  const int w    = tid >> 6;
  const int lane = tid & 63;
  const int q    = lane >> 4;
  const int r    = lane & 15;
  const int nb   = blockIdx.x * BN;
  const int kh   = blockIdx.y;

  // W staging: instr j (0..7) loads rows 2j + (lane>>5), ints 4*(lane&31):
  // two contiguous 512 B spans per instr.
  const int srow = lane >> 5;
  const int skof = 4 * (lane & 31);                 // int offset == bf16 offset
  const int* gW0 = W + (size_t)(nb + w * 16 + srow) * K_SZ
                     + (size_t)kh * KSPAN + skof;
  unsigned short* lw = &lds[w][0];
  const int kbb = kh * (KSPAN / 32);                // base 32-k chunk index
  const int rb  = r * LDB;

  // ---- prologue: issue W_0 then Xr_0 (FIFO order established) ----
  int4 wr[8];
  #pragma unroll
  for (int j = 0; j < 8; ++j) wr[j] = *(const int4*)(gW0 + (size_t)j * 2 * K_SZ);
  uint4 am[8];
  #pragma unroll
  for (int s = 0; s < 4; ++s) {
    am[s * 2 + 0] = Xr[(size_t)((kbb + s) * 2 + 0) * 64 + lane];
    am[s * 2 + 1] = Xr[(size_t)((kbb + s) * 2 + 1) * 64 + lane];
  }

  f32x4 acc0 = {0.f, 0.f, 0.f, 0.f};   // batches 0..15
  f32x4 acc1 = {0.f, 0.f, 0.f, 0.f};   // batches 16..31

  #pragma unroll 1
  for (int h = 0; h < STEPS; ++h) {
    // 1. consume W_h: pack -> LDS (wait leaves Xr_h (+W_{h+1}) in flight)
    #pragma unroll
    for (int j = 0; j < 8; ++j) {
      uint2 p;
      p.x = pack_w(wr[j].x, wr[j].y);
      p.y = pack_w(wr[j].z, wr[j].w);
      *(uint2*)&lw[(2 * j + srow) * LDB + skof] = p;
    }
    // 2. issue W_{h+1} (stays in flight across this step's compute)
    if (h + 1 < STEPS) {
      const int* g = gW0 + (h + 1) * BK;
      #pragma unroll
      for (int j = 0; j < 8; ++j) wr[j] = *(const int4*)(g + (size_t)j * 2 * K_SZ);
    }
    // 3. consume Xr_h via MFMA (wait leaves W_{h+1} in flight);
    //    ds_read after same-wave ds_write is in-order (lgkmcnt only).
    #pragma unroll
    for (int s = 0; s < 4; ++s) {
      bf16x8 Bf = *(const bf16x8*)&lw[rb + s * 32 + q * 8];
      acc0 = __builtin_amdgcn_mfma_f32_16x16x32_bf16(
                 __builtin_bit_cast(bf16x8, am[s * 2 + 0]), Bf, acc0, 0, 0, 0);
      acc1 = __builtin_amdgcn_mfma_f32_16x16x32_bf16(
                 __builtin_bit_cast(bf16x8, am[s * 2 + 1]), Bf, acc1, 0, 0, 0);
    }
    // 4. issue Xr_{h+1} (register WAR on am is safe: MFMAs above already issued)
    if (h + 1 < STEPS) {
      const int kb2 = kbb + (h + 1) * 4;
      #pragma unroll
      for (int s = 0; s < 4; ++s) {
        am[s * 2 + 0] = Xr[(size_t)((kb2 + s) * 2 + 0) * 64 + lane];
        am[s * 2 + 1] = Xr[(size_t)((kb2 + s) * 2 + 1) * 64 + lane];
      }
    }
  }

  // per-kh partials, plain coalesced stores (no atomics)
  const int o = nb + w * 16 + r;        // C/D: col = lane&15
  float* pb = part + (size_t)kh * B_SZ * N_SZ + o;
  #pragma unroll
  for (int rg = 0; rg < 4; ++rg) {      // C/D: row = (lane>>4)*4 + reg
    pb[(size_t)(q * 4 + rg) * N_SZ]      = acc0[rg];
    pb[(size_t)(16 + q * 4 + rg) * N_SZ] = acc1[rg];
  }
}

__global__ void reduce_k(const float* __restrict__ part,
                         const float* __restrict__ ls,
                         const float* __restrict__ bias,
                         float* __restrict__ out) {
  int idx = blockIdx.x * 256 + threadIdx.x;   // idx = b*8192 + o
  int o = idx & (N_SZ - 1);
  float s = 0.f;
  #pragma unroll
  for (int kh = 0; kh < KSPLIT; ++kh)
    s += part[(size_t)kh * B_SZ * N_SZ + idx];
  float sp = log1pf(expf(ls[o]));
  out[idx] = s * fmaxf(sp, 1e-4f) + bias[o];
}

extern "C" void kernel_launch(void* const* d_in, const int* in_sizes, int n_in,
                              void* d_out, int out_size, void* d_ws, size_t ws_size,
                              hipStream_t stream) {
  const float* X  = (const float*)d_in[0];
  const float* ls = (const float*)d_in[1];
  const float* bs = (const float*)d_in[2];
  const int*   W  = (const int*)d_in[3];
  float* out  = (float*)d_out;
  uint4* Xr   = (uint4*)d_ws;                         // 512 KB
  float* part = (float*)((char*)d_ws + (512 << 10));  // KSPLIT MB

  xprep<<<128, 256, 0, stream>>>(X, Xr);
  dim3 grid(N_SZ / BN, KSPLIT);
  tmm<<<grid, 256, 0, stream>>>(W, Xr, part);
  reduce_k<<<(B_SZ * N_SZ) / 256, 256, 0, stream>>>(part, ls, bs, out);
}